// Round 3
// baseline (282.095 us; speedup 1.0000x reference)
//
#include <hip/hip_runtime.h>

// CosineLoss: out = mean_i( 1 - dot(a_i,b_i) / (||a_i||*||b_i||) )
// inputs: d_in[0]=cxr (N,D) f32, d_in[1]=ehr (N,D) f32; N=16384, D=2048.
//
// R6 diagnosis: R4 (2-deep MLP), R5 (16-deep issue burst, VGPR=64), and
// R0 (compact sliding window) ALL land at 96-107us -> per-wave MLP and
// address pattern are refuted as limiters. Common factor: every round ran
// 16 waves/CU. Per-wave completion rate (1KB per ~3.7k cyc) says the
// memory system is starved of INDEPENDENT wave streams (per-wave returns
// are in-order), not stream depth.
//
// R6: one variable changed vs R4 -- occupancy 16 -> 32 waves/CU.
// 2048 blocks x 256 thr, launch_bounds(256,8) = 8 blocks/CU, 2 rows/wave.
// No sched fences (R5 showed they hurt). VGPR must stay <=64.

#define ROWS 16384
#define COLS_V4 512                 // float4 per row (D=2048)
#define BLOCK 256                   // 4 waves per block
#define WPB (BLOCK / 64)            // 4
#define GRID 2048                   // 8 blocks/CU -> 32 waves/CU
#define RPW (ROWS / (GRID * WPB))   // 2 consecutive rows per wave

__global__ __launch_bounds__(BLOCK, 8) void cosine_partial_kernel(
    const float4* __restrict__ A,
    const float4* __restrict__ B,
    float* __restrict__ partial) {
    const int t    = threadIdx.x;
    const int wave = t >> 6;
    const int lane = t & 63;
    const int row0 = (blockIdx.x * WPB + wave) * RPW;

    float wloss = 0.0f;   // meaningful in lane 0 only

    for (int r = 0; r < RPW; ++r) {
        const size_t base = (size_t)(row0 + r) * COLS_V4 + lane;
        const float4* __restrict__ a = A + base;
        const float4* __restrict__ b = B + base;

        float4 va[8], vb[8];
        #pragma unroll
        for (int c = 0; c < 8; ++c) {
            va[c] = a[(size_t)c * 64];
            vb[c] = b[(size_t)c * 64];
        }

        float d = 0.0f, na = 0.0f, nb = 0.0f;
        #pragma unroll
        for (int c = 0; c < 8; ++c) {
            d  += va[c].x * vb[c].x + va[c].y * vb[c].y
                + va[c].z * vb[c].z + va[c].w * vb[c].w;
            na += va[c].x * va[c].x + va[c].y * va[c].y
                + va[c].z * va[c].z + va[c].w * va[c].w;
            nb += vb[c].x * vb[c].x + vb[c].y * vb[c].y
                + vb[c].z * vb[c].z + vb[c].w * vb[c].w;
        }

        // wave reduce, once per 16KB row
        #pragma unroll
        for (int off = 32; off > 0; off >>= 1) {
            d  += __shfl_down(d,  off, 64);
            na += __shfl_down(na, off, 64);
            nb += __shfl_down(nb, off, 64);
        }
        if (lane == 0) wloss += 1.0f - d * rsqrtf(na * nb);
    }

    __shared__ float s_loss[WPB];
    if (lane == 0) s_loss[wave] = wloss;
    __syncthreads();
    if (t == 0) {
        float s = 0.0f;
        #pragma unroll
        for (int w = 0; w < WPB; ++w) s += s_loss[w];
        partial[blockIdx.x] = s;
    }
}

__global__ __launch_bounds__(256) void cosine_reduce_kernel(
    const float* __restrict__ partial,
    float* __restrict__ out) {
    const int t = threadIdx.x;
    float s = 0.0f;
    #pragma unroll
    for (int i = 0; i < GRID / 256; ++i) s += partial[t + i * 256];
    #pragma unroll
    for (int off = 32; off > 0; off >>= 1) s += __shfl_down(s, off, 64);

    __shared__ float s_sum[4];
    const int wave = t >> 6;
    const int lane = t & 63;
    if (lane == 0) s_sum[wave] = s;
    __syncthreads();
    if (t == 0) {
        out[0] = (s_sum[0] + s_sum[1] + s_sum[2] + s_sum[3]) * (1.0f / (float)ROWS);
    }
}

extern "C" void kernel_launch(void* const* d_in, const int* in_sizes, int n_in,
                              void* d_out, int out_size, void* d_ws, size_t ws_size,
                              hipStream_t stream) {
    const float4* cxr = (const float4*)d_in[0];
    const float4* ehr = (const float4*)d_in[1];
    float* out     = (float*)d_out;
    float* partial = (float*)d_ws;   // GRID floats = 8 KB, fully overwritten

    cosine_partial_kernel<<<GRID, BLOCK, 0, stream>>>(cxr, ehr, partial);
    cosine_reduce_kernel<<<1, 256, 0, stream>>>(partial, out);
}

// Round 6
// 258.428 us; speedup vs baseline: 1.0916x; 1.0916x over previous
//
#include <hip/hip_runtime.h>

// CosineLoss: out = mean_i( 1 - dot(a_i,b_i) / (||a_i||*||b_i||) )
// inputs: d_in[0]=cxr (N,D) f32, d_in[1]=ehr (N,D) f32; N=16384, D=2048.
//
// R9 = R7 retry; R8 failed to compile because __builtin_nontemporal_load
// rejects HIP_vector_type<float,4> (struct). Fix: native clang vector
// type (ext_vector_type(4)), same 16B layout, emits global_load_dwordx4 nt.
//
// Diagnosis carried over: concurrency (16 vs 32 waves/CU), MLP depth
// (2 vs 16 in-flight), and address pattern are ALL refuted -- every
// config pins at ~2.7-2.8 TB/s blended read. FETCH=134MB of a 268MB
// stream => ~50% L3 hit: the 268MB cyclic working set thrashes the
// 256MB Infinity Cache every dispatch (LRU-thrash regime). Hypothesis:
// L3 insertion/eviction machinery is the ~2.7 TB/s cap.
//
// Fix under test: A(cxr) loaded NON-TEMPORAL (nt, no L3 insertion) ->
// streams pure HBM; B(ehr, 134MB) then fits entirely in L3 and stays
// resident across dispatches -> two disjoint concurrent supply paths,
// zero thrash. Geometry = proven no-spill R4 shape (VGPR ~36, no fences).

#define ROWS 16384
#define COLS_V4 512                 // float4 per row (D=2048)
#define BLOCK 256                   // 4 waves per block
#define WPB (BLOCK / 64)            // 4
#define GRID 1024                   // 16 waves/CU
#define RPW (ROWS / (GRID * WPB))   // 4 consecutive rows per wave

typedef float v4f __attribute__((ext_vector_type(4)));

__global__ __launch_bounds__(BLOCK, 4) void cosine_partial_kernel(
    const float* __restrict__ A,
    const float* __restrict__ B,
    float* __restrict__ partial) {
    const int t    = threadIdx.x;
    const int wave = t >> 6;
    const int lane = t & 63;
    const int row0 = (blockIdx.x * WPB + wave) * RPW;

    const v4f* __restrict__ A4 = (const v4f*)A;
    const v4f* __restrict__ B4 = (const v4f*)B;

    float wloss = 0.0f;   // meaningful in lane 0 only

    for (int r = 0; r < RPW; ++r) {
        const size_t base = (size_t)(row0 + r) * COLS_V4 + lane;
        const v4f* __restrict__ a = A4 + base;
        const v4f* __restrict__ b = B4 + base;

        v4f va[8], vb[8];
        #pragma unroll
        for (int c = 0; c < 8; ++c) {
            va[c] = __builtin_nontemporal_load(a + (size_t)c * 64);  // nt: bypass L3
            vb[c] = b[(size_t)c * 64];                               // normal: L3-resident
        }

        float d = 0.0f, na = 0.0f, nb = 0.0f;
        #pragma unroll
        for (int c = 0; c < 8; ++c) {
            d  += va[c].x * vb[c].x + va[c].y * vb[c].y
                + va[c].z * vb[c].z + va[c].w * vb[c].w;
            na += va[c].x * va[c].x + va[c].y * va[c].y
                + va[c].z * va[c].z + va[c].w * va[c].w;
            nb += vb[c].x * vb[c].x + vb[c].y * vb[c].y
                + vb[c].z * vb[c].z + vb[c].w * vb[c].w;
        }

        // wave reduce, once per 16KB row
        #pragma unroll
        for (int off = 32; off > 0; off >>= 1) {
            d  += __shfl_down(d,  off, 64);
            na += __shfl_down(na, off, 64);
            nb += __shfl_down(nb, off, 64);
        }
        if (lane == 0) wloss += 1.0f - d * rsqrtf(na * nb);
    }

    __shared__ float s_loss[WPB];
    if (lane == 0) s_loss[wave] = wloss;
    __syncthreads();
    if (t == 0) {
        float s = 0.0f;
        #pragma unroll
        for (int w = 0; w < WPB; ++w) s += s_loss[w];
        partial[blockIdx.x] = s;
    }
}

__global__ __launch_bounds__(256) void cosine_reduce_kernel(
    const float* __restrict__ partial,
    float* __restrict__ out) {
    const int t = threadIdx.x;
    float s = 0.0f;
    #pragma unroll
    for (int i = 0; i < GRID / 256; ++i) s += partial[t + i * 256];
    #pragma unroll
    for (int off = 32; off > 0; off >>= 1) s += __shfl_down(s, off, 64);

    __shared__ float s_sum[4];
    const int wave = t >> 6;
    const int lane = t & 63;
    if (lane == 0) s_sum[wave] = s;
    __syncthreads();
    if (t == 0) {
        out[0] = (s_sum[0] + s_sum[1] + s_sum[2] + s_sum[3]) * (1.0f / (float)ROWS);
    }
}

extern "C" void kernel_launch(void* const* d_in, const int* in_sizes, int n_in,
                              void* d_out, int out_size, void* d_ws, size_t ws_size,
                              hipStream_t stream) {
    const float* cxr = (const float*)d_in[0];
    const float* ehr = (const float*)d_in[1];
    float* out     = (float*)d_out;
    float* partial = (float*)d_ws;   // GRID floats = 4 KB, fully overwritten

    cosine_partial_kernel<<<GRID, BLOCK, 0, stream>>>(cxr, ehr, partial);
    cosine_reduce_kernel<<<1, 256, 0, stream>>>(partial, out);
}

// Round 7
// 248.602 us; speedup vs baseline: 1.1347x; 1.0395x over previous
//
#include <hip/hip_runtime.h>

// CosineLoss: out = mean_i( 1 - dot(a_i,b_i) / (||a_i||*||b_i||) )
// inputs: d_in[0]=cxr (N,D) f32, d_in[1]=ehr (N,D) f32; N=16384, D=2048.
//
// R10. R9 (nt on A only) gave the first real win in 5 rounds: 98.5->79.5us
// with FETCH unchanged (134MB) -> the gain was SERVICE LATENCY (nt skips
// L1/L3 allocation), not hit rate. Confirms per-CU outstanding-request
// budget x latency is the binding constraint (explains wave/MLP/pattern
// insensitivity). Harness fill kernel shows 6.8 TB/s write @ 9.5% occ ->
// fabric has 2x headroom over our 3.4 TB/s delivered read.
//
// R10 change (single variable): nt on BOTH arrays. B trades useless L3
// hits (HBM is half-idle) for the same latency cut A got.
// Check: FETCH_SIZE must jump 134 -> ~268MB (proof nt took effect on B).

#define ROWS 16384
#define COLS_V4 512                 // float4 per row (D=2048)
#define BLOCK 256                   // 4 waves per block
#define WPB (BLOCK / 64)            // 4
#define GRID 1024                   // 16 waves/CU
#define RPW (ROWS / (GRID * WPB))   // 4 consecutive rows per wave

typedef float v4f __attribute__((ext_vector_type(4)));

__global__ __launch_bounds__(BLOCK, 4) void cosine_partial_kernel(
    const float* __restrict__ A,
    const float* __restrict__ B,
    float* __restrict__ partial) {
    const int t    = threadIdx.x;
    const int wave = t >> 6;
    const int lane = t & 63;
    const int row0 = (blockIdx.x * WPB + wave) * RPW;

    const v4f* __restrict__ A4 = (const v4f*)A;
    const v4f* __restrict__ B4 = (const v4f*)B;

    float wloss = 0.0f;   // meaningful in lane 0 only

    for (int r = 0; r < RPW; ++r) {
        const size_t base = (size_t)(row0 + r) * COLS_V4 + lane;
        const v4f* __restrict__ a = A4 + base;
        const v4f* __restrict__ b = B4 + base;

        v4f va[8], vb[8];
        #pragma unroll
        for (int c = 0; c < 8; ++c) {
            va[c] = __builtin_nontemporal_load(a + (size_t)c * 64);  // nt
            vb[c] = __builtin_nontemporal_load(b + (size_t)c * 64);  // nt
        }

        float d = 0.0f, na = 0.0f, nb = 0.0f;
        #pragma unroll
        for (int c = 0; c < 8; ++c) {
            d  += va[c].x * vb[c].x + va[c].y * vb[c].y
                + va[c].z * vb[c].z + va[c].w * vb[c].w;
            na += va[c].x * va[c].x + va[c].y * va[c].y
                + va[c].z * va[c].z + va[c].w * va[c].w;
            nb += vb[c].x * vb[c].x + vb[c].y * vb[c].y
                + vb[c].z * vb[c].z + vb[c].w * vb[c].w;
        }

        // wave reduce, once per 16KB row
        #pragma unroll
        for (int off = 32; off > 0; off >>= 1) {
            d  += __shfl_down(d,  off, 64);
            na += __shfl_down(na, off, 64);
            nb += __shfl_down(nb, off, 64);
        }
        if (lane == 0) wloss += 1.0f - d * rsqrtf(na * nb);
    }

    __shared__ float s_loss[WPB];
    if (lane == 0) s_loss[wave] = wloss;
    __syncthreads();
    if (t == 0) {
        float s = 0.0f;
        #pragma unroll
        for (int w = 0; w < WPB; ++w) s += s_loss[w];
        partial[blockIdx.x] = s;
    }
}

__global__ __launch_bounds__(256) void cosine_reduce_kernel(
    const float* __restrict__ partial,
    float* __restrict__ out) {
    const int t = threadIdx.x;
    float s = 0.0f;
    #pragma unroll
    for (int i = 0; i < GRID / 256; ++i) s += partial[t + i * 256];
    #pragma unroll
    for (int off = 32; off > 0; off >>= 1) s += __shfl_down(s, off, 64);

    __shared__ float s_sum[4];
    const int wave = t >> 6;
    const int lane = t & 63;
    if (lane == 0) s_sum[wave] = s;
    __syncthreads();
    if (t == 0) {
        out[0] = (s_sum[0] + s_sum[1] + s_sum[2] + s_sum[3]) * (1.0f / (float)ROWS);
    }
}

extern "C" void kernel_launch(void* const* d_in, const int* in_sizes, int n_in,
                              void* d_out, int out_size, void* d_ws, size_t ws_size,
                              hipStream_t stream) {
    const float* cxr = (const float*)d_in[0];
    const float* ehr = (const float*)d_in[1];
    float* out     = (float*)d_out;
    float* partial = (float*)d_ws;   // GRID floats = 4 KB, fully overwritten

    cosine_partial_kernel<<<GRID, BLOCK, 0, stream>>>(cxr, ehr, partial);
    cosine_reduce_kernel<<<1, 256, 0, stream>>>(partial, out);
}